// Round 4
// baseline (366.398 us; speedup 1.0000x reference)
//
#include <hip/hip_runtime.h>
#include <math.h>

#define CHUNK 32
#define DK 128
#define DV 128
#define L_SEQ 4096
#define BH 32
#define NCH 128
#define NSC 64

typedef __attribute__((ext_vector_type(8))) short bf16x8;
typedef __attribute__((ext_vector_type(4))) float f32x4;

union U8 { unsigned int u[4]; bf16x8 v; };

#define MFMA16(a, b, c) __builtin_amdgcn_mfma_f32_16x16x32_bf16((a), (b), (c), 0, 0, 0)
#define LGKM_WAIT() __asm__ __volatile__("s_waitcnt lgkmcnt(0)" ::: "memory")

__device__ __forceinline__ unsigned short f2bf(float x){
    unsigned int u = __builtin_bit_cast(unsigned int, x);
    u = u + 0x7FFFu + ((u >> 16) & 1u);   // RNE
    return (unsigned short)(u >> 16);
}
// RNE pack of two f32 -> packed bf16 pair, single HW instruction.
__device__ __forceinline__ unsigned int pk2(float a, float b){
    unsigned int r;
    asm("v_cvt_pk_bf16_f32 %0, %1, %2" : "=v"(r) : "v"(a), "v"(b));
    return r;
}

__device__ __forceinline__ bf16x8 afragF32(const float (*M)[36], int row, int q8){
    float4 f0 = *(const float4*)&M[row][q8];
    float4 f1 = *(const float4*)&M[row][q8 + 4];
    U8 t;
    t.u[0] = pk2(f0.x, f0.y); t.u[1] = pk2(f0.z, f0.w);
    t.u[2] = pk2(f1.x, f1.y); t.u[3] = pk2(f1.z, f1.w);
    return t.v;
}
__device__ __forceinline__ bf16x8 bfragF32(const float (*M)[36], int q8, int col){
    U8 t;
#pragma unroll
    for (int j2 = 0; j2 < 4; ++j2)
        t.u[j2] = pk2(M[q8 + 2*j2][col], M[q8 + 2*j2 + 1][col]);
    return t.v;
}

// ============== Phase 1: per-SUPERCHUNK prep (64 rows/block) ===============
// Outputs per chunk: qw/kw (bf16 rows), Tw (T0/T1), Aw (tril attn), kwT.
// Per superchunk: Gw = kb_o kn_e^T (full, bf16), Fw = qn_o kn_e^T (full).
// NO L materialization (bf16 triple-product was the round-3 accuracy bug);
// the scan composes U_o = T1 (X_o - G U_e) sequentially instead.

__global__ __launch_bounds__(64)
void prep64_kernel(const float* __restrict__ q, const float* __restrict__ k,
                   const float* __restrict__ beta,
                   unsigned short* __restrict__ qw, unsigned short* __restrict__ kw,
                   unsigned short* __restrict__ Tw, unsigned short* __restrict__ Aw,
                   unsigned short* __restrict__ kwT,
                   unsigned short* __restrict__ Gw, unsigned short* __restrict__ Fw)
{
    const int sb = blockIdx.x;                 // bh*NSC + su
    const size_t row0 = (size_t)sb * 64;
    const int bcE = 2*sb, bcO = 2*sb + 1;      // global chunk ids
    const int l = threadIdx.x;
    const int quad = (l >> 4) & 3, ln15 = l & 15, q8 = quad * 8;

    __shared__ float Ms[32][36];
    __shared__ float Rs[32][36];
    __shared__ __align__(16) unsigned short knS[4392];

    const f32x4 Z = {0.f, 0.f, 0.f, 0.f};

    auto loadnormQ = [&](size_t r0, bf16x8 (&qF)[2][4]){
        float4 raw[2][4][2];
        float s0 = 0.f, s1 = 0.f;
#pragma unroll
        for (int mt = 0; mt < 2; ++mt)
#pragma unroll
        for (int ks = 0; ks < 4; ++ks){
            const float* p = q + (r0 + 16*mt + ln15) * DK + 32*ks + q8;
            raw[mt][ks][0] = *(const float4*)p;
            raw[mt][ks][1] = *(const float4*)(p + 4);
        }
#pragma unroll
        for (int ks = 0; ks < 4; ++ks)
#pragma unroll
        for (int h = 0; h < 2; ++h){
            float4 a = raw[0][ks][h], b = raw[1][ks][h];
            s0 += a.x*a.x + a.y*a.y + a.z*a.z + a.w*a.w;
            s1 += b.x*b.x + b.y*b.y + b.z*b.z + b.w*b.w;
        }
        s0 += __shfl_xor(s0, 16); s0 += __shfl_xor(s0, 32);
        s1 += __shfl_xor(s1, 16); s1 += __shfl_xor(s1, 32);
        float sc0 = rsqrtf(s0 + 1e-6f), sc1 = rsqrtf(s1 + 1e-6f);
#pragma unroll
        for (int mt = 0; mt < 2; ++mt){
            float sc = mt ? sc1 : sc0;
#pragma unroll
            for (int ks = 0; ks < 4; ++ks){
                float4 a = raw[mt][ks][0], b = raw[mt][ks][1];
                U8 t;
                t.u[0] = pk2(a.x*sc, a.y*sc); t.u[1] = pk2(a.z*sc, a.w*sc);
                t.u[2] = pk2(b.x*sc, b.y*sc); t.u[3] = pk2(b.z*sc, b.w*sc);
                qF[mt][ks] = t.v;
                *(bf16x8*)(qw + (r0 + 16*mt + ln15) * DK + 32*ks + q8) = t.v;
            }
        }
    };
    auto loadnormK = [&](size_t r0, bf16x8 (&kF)[2][4], bf16x8 (&kB)[2][4]){
        const float b0 = beta[r0 + ln15];
        const float b1 = beta[r0 + 16 + ln15];
        float4 raw[2][4][2];
        float s0 = 0.f, s1 = 0.f;
#pragma unroll
        for (int mt = 0; mt < 2; ++mt)
#pragma unroll
        for (int ks = 0; ks < 4; ++ks){
            const float* p = k + (r0 + 16*mt + ln15) * DK + 32*ks + q8;
            raw[mt][ks][0] = *(const float4*)p;
            raw[mt][ks][1] = *(const float4*)(p + 4);
        }
#pragma unroll
        for (int ks = 0; ks < 4; ++ks)
#pragma unroll
        for (int h = 0; h < 2; ++h){
            float4 a = raw[0][ks][h], b = raw[1][ks][h];
            s0 += a.x*a.x + a.y*a.y + a.z*a.z + a.w*a.w;
            s1 += b.x*b.x + b.y*b.y + b.z*b.z + b.w*b.w;
        }
        s0 += __shfl_xor(s0, 16); s0 += __shfl_xor(s0, 32);
        s1 += __shfl_xor(s1, 16); s1 += __shfl_xor(s1, 32);
        float sc0 = rsqrtf(s0 + 1e-6f), sc1 = rsqrtf(s1 + 1e-6f);
#pragma unroll
        for (int mt = 0; mt < 2; ++mt){
            float sc = mt ? sc1 : sc0;
            float bb = mt ? b1 : b0;
#pragma unroll
            for (int ks = 0; ks < 4; ++ks){
                float4 a = raw[mt][ks][0], b = raw[mt][ks][1];
                float x0=a.x*sc, x1=a.y*sc, x2=a.z*sc, x3=a.w*sc;
                float x4=b.x*sc, x5=b.y*sc, x6=b.z*sc, x7=b.w*sc;
                U8 t, tb;
                t.u[0]=pk2(x0,x1); t.u[1]=pk2(x2,x3); t.u[2]=pk2(x4,x5); t.u[3]=pk2(x6,x7);
                tb.u[0]=pk2(x0*bb,x1*bb); tb.u[1]=pk2(x2*bb,x3*bb);
                tb.u[2]=pk2(x4*bb,x5*bb); tb.u[3]=pk2(x6*bb,x7*bb);
                kF[mt][ks] = t.v; kB[mt][ks] = tb.v;
                *(bf16x8*)(kw + (r0 + 16*mt + ln15) * DK + 32*ks + q8) = t.v;
            }
        }
    };
    auto stageKnS = [&](bf16x8 (&kF)[2][4]){
#pragma unroll
        for (int mt = 0; mt < 2; ++mt)
#pragma unroll
        for (int ks = 0; ks < 4; ++ks){
            int i = 16*mt + ln15;
            int ad = i * 136 + (i >> 3) * 16 + 32*ks + q8;
            *(bf16x8*)&knS[ad] = kF[mt][ks];
        }
    };
    auto gatherKwT = [&](int bc){
        unsigned short* kT = kwT + ((size_t)bc << 12);
#pragma unroll
        for (int t = 0; t < 8; ++t){
            unsigned short rj[8];
#pragma unroll
            for (int j = 0; j < 8; ++j)
                rj[j] = knS[(q8 + j) * 136 + ((q8 + j) >> 3) * 16 + 16*t + ln15];
            U8 kk;
            kk.u[0] = (unsigned)rj[0] | ((unsigned)rj[1] << 16);
            kk.u[1] = (unsigned)rj[2] | ((unsigned)rj[3] << 16);
            kk.u[2] = (unsigned)rj[4] | ((unsigned)rj[5] << 16);
            kk.u[3] = (unsigned)rj[6] | ((unsigned)rj[7] << 16);
            *(bf16x8*)(kT + (16*t + ln15) * 32 + q8) = kk.v;
        }
    };
    // Newton-doubling inversion: Ms holds strict-lower(-B) on entry; Rc = I + that.
    auto invert32 = [&](f32x4 (&Rc)[2][2]){
#pragma unroll 1
        for (int rd = 0; rd < 4; ++rd){
            LGKM_WAIT();
            bf16x8 Am[2], Bm2[2];
#pragma unroll
            for (int mt = 0; mt < 2; ++mt) Am[mt] = afragF32(Ms, 16*mt + ln15, q8);
#pragma unroll
            for (int nt = 0; nt < 2; ++nt) Bm2[nt] = bfragF32(Ms, q8, 16*nt + ln15);
            f32x4 Mq[2][2];
#pragma unroll
            for (int mt = 0; mt < 2; ++mt)
#pragma unroll
            for (int nt = 0; nt < 2; ++nt)
                Mq[mt][nt] = MFMA16(Am[mt], Bm2[nt], Z);
#pragma unroll
            for (int mt = 0; mt < 2; ++mt)
#pragma unroll
            for (int nt = 0; nt < 2; ++nt)
#pragma unroll
            for (int rg = 0; rg < 4; ++rg){
                int row = 16*mt + 4*quad + rg, col = 16*nt + ln15;
                Rs[row][col] = Rc[mt][nt][rg];
                Ms[row][col] = Mq[mt][nt][rg];
            }
            LGKM_WAIT();
            bf16x8 Ar[2], Bq[2];
#pragma unroll
            for (int mt = 0; mt < 2; ++mt) Ar[mt] = afragF32(Rs, 16*mt + ln15, q8);
#pragma unroll
            for (int nt = 0; nt < 2; ++nt) Bq[nt] = bfragF32(Ms, q8, 16*nt + ln15);
#pragma unroll
            for (int mt = 0; mt < 2; ++mt)
#pragma unroll
            for (int nt = 0; nt < 2; ++nt)
                Rc[mt][nt] = MFMA16(Ar[mt], Bq[nt], Rc[mt][nt]);
        }
    };

    // ---------------- phase E (chunk bcE, rows row0..row0+31) ----------------
    bf16x8 qFe[2][4], kFe[2][4], kBe[2][4];
    loadnormQ(row0, qFe);
    loadnormK(row0, kFe, kBe);
    stageKnS(kFe);

    f32x4 Bacc[2][2] = {{Z,Z},{Z,Z}}, Aacc[2][2] = {{Z,Z},{Z,Z}};
#pragma unroll
    for (int ks = 0; ks < 4; ++ks)
#pragma unroll
    for (int mt = 0; mt < 2; ++mt)
#pragma unroll
    for (int nt = 0; nt < 2; ++nt){
        Bacc[mt][nt] = MFMA16(kBe[mt][ks], kFe[nt][ks], Bacc[mt][nt]);
        Aacc[mt][nt] = MFMA16(qFe[mt][ks], kFe[nt][ks], Aacc[mt][nt]);
    }
    f32x4 Rc[2][2];
#pragma unroll
    for (int mt = 0; mt < 2; ++mt)
#pragma unroll
    for (int nt = 0; nt < 2; ++nt)
#pragma unroll
    for (int rg = 0; rg < 4; ++rg){
        int row = 16*mt + 4*quad + rg, col = 16*nt + ln15;
        float av = (col <= row) ? Aacc[mt][nt][rg] : 0.f;
        Aw[((size_t)bcE << 10) + row*32 + col] = f2bf(av);
        float bm = (col < row) ? -Bacc[mt][nt][rg] : 0.f;
        Ms[row][col] = bm;
        Rc[mt][nt][rg] = bm + ((col == row) ? 1.f : 0.f);
    }
    gatherKwT(bcE);
    invert32(Rc);                       // Rc = T0
#pragma unroll
    for (int mt = 0; mt < 2; ++mt)
#pragma unroll
    for (int nt = 0; nt < 2; ++nt)
#pragma unroll
    for (int rg = 0; rg < 4; ++rg){
        int row = 16*mt + 4*quad + rg, col = 16*nt + ln15;
        Tw[((size_t)bcE << 10) + row*32 + col] = f2bf(Rc[mt][nt][rg]);
    }

    // ---------------- phase O (chunk bcO, rows row0+32..row0+63) -------------
    bf16x8 qFo[2][4], kFo[2][4], kBo[2][4];
    loadnormQ(row0 + 32, qFo);
    loadnormK(row0 + 32, kFo, kBo);
    LGKM_WAIT();                        // phase-E knS reads complete before re-stage
    stageKnS(kFo);

    f32x4 Gacc[2][2] = {{Z,Z},{Z,Z}}, Facc[2][2] = {{Z,Z},{Z,Z}};
    f32x4 Bo[2][2]   = {{Z,Z},{Z,Z}}, Ao[2][2]   = {{Z,Z},{Z,Z}};
#pragma unroll
    for (int ks = 0; ks < 4; ++ks)
#pragma unroll
    for (int mt = 0; mt < 2; ++mt)
#pragma unroll
    for (int nt = 0; nt < 2; ++nt){
        Gacc[mt][nt] = MFMA16(kBo[mt][ks], kFe[nt][ks], Gacc[mt][nt]);
        Facc[mt][nt] = MFMA16(qFo[mt][ks], kFe[nt][ks], Facc[mt][nt]);
        Bo[mt][nt]   = MFMA16(kBo[mt][ks], kFo[nt][ks], Bo[mt][nt]);
        Ao[mt][nt]   = MFMA16(qFo[mt][ks], kFo[nt][ks], Ao[mt][nt]);
    }
#pragma unroll
    for (int mt = 0; mt < 2; ++mt)
#pragma unroll
    for (int nt = 0; nt < 2; ++nt)
#pragma unroll
    for (int rg = 0; rg < 4; ++rg){
        int row = 16*mt + 4*quad + rg, col = 16*nt + ln15;
        Fw[((size_t)sb << 10) + row*32 + col] = f2bf(Facc[mt][nt][rg]);
        Gw[((size_t)sb << 10) + row*32 + col] = f2bf(Gacc[mt][nt][rg]);
        float av = (col <= row) ? Ao[mt][nt][rg] : 0.f;
        Aw[((size_t)bcO << 10) + row*32 + col] = f2bf(av);
        float bm = (col < row) ? -Bo[mt][nt][rg] : 0.f;
        Ms[row][col] = bm;
        Rc[mt][nt][rg] = bm + ((col == row) ? 1.f : 0.f);
    }
    gatherKwT(bcO);
    invert32(Rc);                       // Rc = T1
#pragma unroll
    for (int mt = 0; mt < 2; ++mt)
#pragma unroll
    for (int nt = 0; nt < 2; ++nt)
#pragma unroll
    for (int rg = 0; rg < 4; ++rg){
        int row = 16*mt + 4*quad + rg, col = 16*nt + ln15;
        Tw[((size_t)bcO << 10) + row*32 + col] = f2bf(Rc[mt][nt][rg]);
    }
}

// ============== Phase 2: superchunk scan, 64 rows/body =====================
// 1 wave/block, zero LDS, 64 sequential bodies. Odd half composed
// sequentially: U_o = T1 (X_o - G U_e) — no bf16 L matrix.

__global__ __launch_bounds__(64, 1)
void scan64(const float* __restrict__ v, const float* __restrict__ beta,
            const unsigned short* __restrict__ qw, const unsigned short* __restrict__ kw,
            const unsigned short* __restrict__ kwT, const unsigned short* __restrict__ Tw,
            const unsigned short* __restrict__ Aw, const unsigned short* __restrict__ Gw,
            const unsigned short* __restrict__ Fw, float* __restrict__ out)
{
    const int id = blockIdx.x;
    const int bh = id & 31, cb = id >> 5, c0 = cb * 16;
    const int l = threadIdx.x;
    const int quad = (l >> 4) & 3, ln15 = l & 15, q8 = quad * 8;
    const int hi = l >> 5;
    const f32x4 Z = {0.f, 0.f, 0.f, 0.f};

    f32x4 Sacc[8];
#pragma unroll
    for (int t = 0; t < 8; ++t) Sacc[t] = Z;

    const size_t bhL = (size_t)bh * L_SEQ;
    const int a0 = (((l & 16) << 1) | ln15) << 2;
    const int a1 = a0 + 64;

    auto quadswap = [&](int p0, int p1, int p2, int p3) -> bf16x8 {
        U8 r; int e, f;
        e = __builtin_amdgcn_ds_bpermute(a0, p0); f = __builtin_amdgcn_ds_bpermute(a0, p2);
        r.u[0] = (unsigned)(hi ? f : e);
        e = __builtin_amdgcn_ds_bpermute(a0, p1); f = __builtin_amdgcn_ds_bpermute(a0, p3);
        r.u[1] = (unsigned)(hi ? f : e);
        e = __builtin_amdgcn_ds_bpermute(a1, p0); f = __builtin_amdgcn_ds_bpermute(a1, p2);
        r.u[2] = (unsigned)(hi ? f : e);
        e = __builtin_amdgcn_ds_bpermute(a1, p1); f = __builtin_amdgcn_ds_bpermute(a1, p3);
        r.u[3] = (unsigned)(hi ? f : e);
        return r.v;
    };

    bf16x8 knF[4][4], qA[4][4], knAe[8], knAo[8];
    bf16x8 t0A[2], t1A[2], gA[2], aAe[2], aAo[2], fA[2];
    bf16x8 uBe, uBo;
    float vr[16], br[16];

    auto loadKF = [&](int sc){
        const unsigned short* p = kw + (bhL + (size_t)sc * 64) * DK;
#pragma unroll
        for (int mt = 0; mt < 4; ++mt)
#pragma unroll
        for (int ks = 0; ks < 4; ++ks)
            knF[mt][ks] = *(const bf16x8*)(p + (16*mt + ln15) * DK + 32*ks + q8);
    };
    auto loadQA = [&](int sc){
        const unsigned short* p = qw + (bhL + (size_t)sc * 64) * DK;
#pragma unroll
        for (int mt = 0; mt < 4; ++mt)
#pragma unroll
        for (int ks = 0; ks < 4; ++ks)
            qA[mt][ks] = *(const bf16x8*)(p + (16*mt + ln15) * DK + 32*ks + q8);
    };
    auto loadKT = [&](int sc){
        const unsigned short* p = kwT + ((size_t)(bh * NCH + 2*sc) << 12);
#pragma unroll
        for (int t = 0; t < 8; ++t)
            knAe[t] = *(const bf16x8*)(p + (16*t + ln15) * 32 + q8);
        p += 4096;
#pragma unroll
        for (int t = 0; t < 8; ++t)
            knAo[t] = *(const bf16x8*)(p + (16*t + ln15) * 32 + q8);
    };
    auto loadTLAF = [&](int sc){
        const unsigned short* pT = Tw + ((size_t)(bh * NCH + 2*sc) << 10);
        const unsigned short* pA = Aw + ((size_t)(bh * NCH + 2*sc) << 10);
        const unsigned short* pG = Gw + ((size_t)(bh * NSC + sc) << 10);
        const unsigned short* pF = Fw + ((size_t)(bh * NSC + sc) << 10);
#pragma unroll
        for (int m = 0; m < 2; ++m){
            int off = (16*m + ln15) * 32 + q8;
            t0A[m] = *(const bf16x8*)(pT + off);
            t1A[m] = *(const bf16x8*)(pT + 1024 + off);
            gA[m]  = *(const bf16x8*)(pG + off);
            aAe[m] = *(const bf16x8*)(pA + off);
            aAo[m] = *(const bf16x8*)(pA + 1024 + off);
            fA[m]  = *(const bf16x8*)(pF + off);
        }
    };
    auto loadVB = [&](int sc){
        const size_t r0 = bhL + (size_t)sc * 64;
#pragma unroll
        for (int mt = 0; mt < 4; ++mt)
#pragma unroll
        for (int rg = 0; rg < 4; ++rg){
            int i = 16*mt + 4*quad + rg;
            vr[4*mt+rg] = v[(r0 + i) * DV + c0 + ln15];
            br[4*mt+rg] = beta[r0 + i];
        }
    };

    // prologue
    loadKF(0); loadQA(0); loadVB(0);
    {
        U8 z; z.u[0]=0u; z.u[1]=0u; z.u[2]=0u; z.u[3]=0u;
        uBe = z.v; uBo = z.v;
#pragma unroll
        for (int t = 0; t < 8; ++t){ knAe[t] = z.v; knAo[t] = z.v; }
    }

    for (int sc = 0; sc < NSC; ++sc){
        const size_t r0 = bhL + (size_t)sc * 64;
        const int scn = (sc + 1 < NSC) ? sc + 1 : NSC - 1;

        // current-sc small matrices (used mid/late body)
        loadTLAF(sc);

        // (1) S += knT(sc-1) @ U(sc-1)   (zeros at sc=0)
#pragma unroll
        for (int t = 0; t < 8; ++t) Sacc[t] = MFMA16(knAe[t], uBe, Sacc[t]);
#pragma unroll
        for (int t = 0; t < 8; ++t) Sacc[t] = MFMA16(knAo[t], uBo, Sacc[t]);

        // (1b) knT(sc) for next body's S-update
        loadKT(sc);

        // (2) S -> bf16 pairs -> B-frags
        int P[8][2];
#pragma unroll
        for (int t = 0; t < 8; ++t){
            P[t][0] = (int)pk2(Sacc[t][0], Sacc[t][1]);
            P[t][1] = (int)pk2(Sacc[t][2], Sacc[t][3]);
        }
        bf16x8 SB[4];
#pragma unroll
        for (int ks = 0; ks < 4; ++ks)
            SB[ks] = quadswap(P[2*ks][0], P[2*ks][1], P[2*ks+1][0], P[2*ks+1][1]);

        // (3) Y = kn @ S ; Op = qn @ S   (64 rows)
        f32x4 Y[4] = {Z,Z,Z,Z}, Op[4] = {Z,Z,Z,Z};
#pragma unroll
        for (int ks = 0; ks < 4; ++ks)
#pragma unroll
        for (int mt = 0; mt < 4; ++mt){
            Y[mt]  = MFMA16(knF[mt][ks], SB[ks], Y[mt]);
            Op[mt] = MFMA16(qA[mt][ks],  SB[ks], Op[mt]);
        }

        // (3b) prefetch kn/q(sc+1)
        loadKF(scn); loadQA(scn);

        // (4) X_e = beta*(v - Y) even half -> B-frag
        int PXE[2][2];
#pragma unroll
        for (int mt = 0; mt < 2; ++mt){
            float x0 = br[4*mt+0] * (vr[4*mt+0] - Y[mt][0]);
            float x1 = br[4*mt+1] * (vr[4*mt+1] - Y[mt][1]);
            float x2 = br[4*mt+2] * (vr[4*mt+2] - Y[mt][2]);
            float x3 = br[4*mt+3] * (vr[4*mt+3] - Y[mt][3]);
            PXE[mt][0] = (int)pk2(x0, x1);
            PXE[mt][1] = (int)pk2(x2, x3);
        }
        bf16x8 Xb0 = quadswap(PXE[0][0], PXE[0][1], PXE[1][0], PXE[1][1]);

        // (5) U_e = T0 @ X_e
        f32x4 U0 = MFMA16(t0A[0], Xb0, Z);
        f32x4 U1 = MFMA16(t0A[1], Xb0, Z);

        // (6) uBe
        uBe = quadswap((int)pk2(U0[0],U0[1]), (int)pk2(U0[2],U0[3]),
                       (int)pk2(U1[0],U1[1]), (int)pk2(U1[2],U1[3]));

        // (7) Gc = G @ U_e ; X_o' = beta*(v - Y)_odd - Gc -> B-frag
        f32x4 Gc0 = MFMA16(gA[0], uBe, Z);
        f32x4 Gc1 = MFMA16(gA[1], uBe, Z);
        int PXO[2][2];
        {
            float x0 = br[8]  * (vr[8]  - Y[2][0]) - Gc0[0];
            float x1 = br[9]  * (vr[9]  - Y[2][1]) - Gc0[1];
            float x2 = br[10] * (vr[10] - Y[2][2]) - Gc0[2];
            float x3 = br[11] * (vr[11] - Y[2][3]) - Gc0[3];
            PXO[0][0] = (int)pk2(x0, x1); PXO[0][1] = (int)pk2(x2, x3);
            float y0 = br[12] * (vr[12] - Y[3][0]) - Gc1[0];
            float y1 = br[13] * (vr[13] - Y[3][1]) - Gc1[1];
            float y2 = br[14] * (vr[14] - Y[3][2]) - Gc1[2];
            float y3 = br[15] * (vr[15] - Y[3][3]) - Gc1[3];
            PXO[1][0] = (int)pk2(y0, y1); PXO[1][1] = (int)pk2(y2, y3);
        }
        bf16x8 Xb1 = quadswap(PXO[0][0], PXO[0][1], PXO[1][0], PXO[1][1]);

        // (7b) prefetch v/beta(sc+1)  (after last vr/br use)
        loadVB(scn);

        // (8) U_o = T1 @ X_o'
        f32x4 U2 = MFMA16(t1A[0], Xb1, Z);
        f32x4 U3 = MFMA16(t1A[1], Xb1, Z);

        // (9) uBo
        uBo = quadswap((int)pk2(U2[0],U2[1]), (int)pk2(U2[2],U2[3]),
                       (int)pk2(U3[0],U3[1]), (int)pk2(U3[2],U3[3]));

        // (10) O = Op + attn64 @ U ; store
        f32x4 O[4];
        O[0] = MFMA16(aAe[0], uBe, Op[0]);
        O[1] = MFMA16(aAe[1], uBe, Op[1]);
        O[2] = MFMA16(fA[0], uBe, Op[2]); O[2] = MFMA16(aAo[0], uBo, O[2]);
        O[3] = MFMA16(fA[1], uBe, Op[3]); O[3] = MFMA16(aAo[1], uBo, O[3]);
#pragma unroll
        for (int mt = 0; mt < 4; ++mt)
#pragma unroll
        for (int rg = 0; rg < 4; ++rg)
            out[(r0 + 16*mt + 4*quad + rg) * DV + c0 + ln15] = O[mt][rg];
    }
}

// ============== Fallback tier 1: round-2 prep + scan_fast (ws>=117.4MB) ====

__global__ __launch_bounds__(64)
void prep_kernel(const float* __restrict__ q, const float* __restrict__ k,
                 const float* __restrict__ beta,
                 unsigned short* __restrict__ qw, unsigned short* __restrict__ kw,
                 unsigned short* __restrict__ Tw, unsigned short* __restrict__ Aw,
                 unsigned short* __restrict__ kwT)
{
    const int bc = blockIdx.x;
    const size_t row0 = (size_t)bc * CHUNK;
    const int l = threadIdx.x;
    const int quad = (l >> 4) & 3, ln15 = l & 15, q8 = quad * 8;

    __shared__ float Ms[32][36];
    __shared__ float Rs[32][36];
    __shared__ unsigned short knS[4392];

    const float bet0 = beta[row0 + ln15];
    const float bet1 = beta[row0 + 16 + ln15];

    bf16x8 qF[2][4];
    {
        float4 raw[2][4][2];
        float s0 = 0.f, s1 = 0.f;
#pragma unroll
        for (int mt = 0; mt < 2; ++mt)
#pragma unroll
        for (int ks = 0; ks < 4; ++ks){
            const float* p = q + (row0 + 16*mt + ln15) * DK + 32*ks + q8;
            raw[mt][ks][0] = *(const float4*)p;
            raw[mt][ks][1] = *(const float4*)(p + 4);
        }
#pragma unroll
        for (int ks = 0; ks < 4; ++ks)
#pragma unroll
        for (int h = 0; h < 2; ++h){
            float4 a = raw[0][ks][h], b = raw[1][ks][h];
            s0 += a.x*a.x + a.y*a.y + a.z*a.z + a.w*a.w;
            s1 += b.x*b.x + b.y*b.y + b.z*b.z + b.w*b.w;
        }
        s0 += __shfl_xor(s0, 16); s0 += __shfl_xor(s0, 32);
        s1 += __shfl_xor(s1, 16); s1 += __shfl_xor(s1, 32);
        float sc0 = rsqrtf(s0 + 1e-6f), sc1 = rsqrtf(s1 + 1e-6f);
#pragma unroll
        for (int mt = 0; mt < 2; ++mt){
            float sc = mt ? sc1 : sc0;
#pragma unroll
            for (int ks = 0; ks < 4; ++ks){
                float4 a = raw[mt][ks][0], b = raw[mt][ks][1];
                U8 t;
                t.u[0] = pk2(a.x*sc, a.y*sc); t.u[1] = pk2(a.z*sc, a.w*sc);
                t.u[2] = pk2(b.x*sc, b.y*sc); t.u[3] = pk2(b.z*sc, b.w*sc);
                qF[mt][ks] = t.v;
                *(bf16x8*)(qw + (row0 + 16*mt + ln15) * DK + 32*ks + q8) = t.v;
            }
        }
    }
    bf16x8 kF[2][4], kB[2][4];
    {
        float4 raw[2][4][2];
        float s0 = 0.f, s1 = 0.f;
#pragma unroll
        for (int mt = 0; mt < 2; ++mt)
#pragma unroll
        for (int ks = 0; ks < 4; ++ks){
            const float* p = k + (row0 + 16*mt + ln15) * DK + 32*ks + q8;
            raw[mt][ks][0] = *(const float4*)p;
            raw[mt][ks][1] = *(const float4*)(p + 4);
        }
#pragma unroll
        for (int ks = 0; ks < 4; ++ks)
#pragma unroll
        for (int h = 0; h < 2; ++h){
            float4 a = raw[0][ks][h], b = raw[1][ks][h];
            s0 += a.x*a.x + a.y*a.y + a.z*a.z + a.w*a.w;
            s1 += b.x*b.x + b.y*b.y + b.z*b.z + b.w*b.w;
        }
        s0 += __shfl_xor(s0, 16); s0 += __shfl_xor(s0, 32);
        s1 += __shfl_xor(s1, 16); s1 += __shfl_xor(s1, 32);
        float sc0 = rsqrtf(s0 + 1e-6f), sc1 = rsqrtf(s1 + 1e-6f);
#pragma unroll
        for (int mt = 0; mt < 2; ++mt){
            float sc = mt ? sc1 : sc0;
            float bb = mt ? bet1 : bet0;
#pragma unroll
            for (int ks = 0; ks < 4; ++ks){
                float4 a = raw[mt][ks][0], b = raw[mt][ks][1];
                float x0=a.x*sc, x1=a.y*sc, x2=a.z*sc, x3=a.w*sc;
                float x4=b.x*sc, x5=b.y*sc, x6=b.z*sc, x7=b.w*sc;
                U8 t, tb;
                t.u[0]=pk2(x0,x1); t.u[1]=pk2(x2,x3); t.u[2]=pk2(x4,x5); t.u[3]=pk2(x6,x7);
                tb.u[0]=pk2(x0*bb,x1*bb); tb.u[1]=pk2(x2*bb,x3*bb);
                tb.u[2]=pk2(x4*bb,x5*bb); tb.u[3]=pk2(x6*bb,x7*bb);
                kF[mt][ks] = t.v; kB[mt][ks] = tb.v;
                *(bf16x8*)(kw + (row0 + 16*mt + ln15) * DK + 32*ks + q8) = t.v;
            }
        }
    }
#pragma unroll
    for (int mt = 0; mt < 2; ++mt)
#pragma unroll
    for (int ks = 0; ks < 4; ++ks){
        int i = 16*mt + ln15;
        int ad = i * 136 + (i >> 3) * 16 + 32*ks + q8;
        *(bf16x8*)&knS[ad] = kF[mt][ks];
    }
    f32x4 Z = {0.f, 0.f, 0.f, 0.f};
    f32x4 Bacc[2][2] = {{Z, Z}, {Z, Z}};
    f32x4 Aacc[2][2] = {{Z, Z}, {Z, Z}};
#pragma unroll
    for (int ks = 0; ks < 4; ++ks)
#pragma unroll
    for (int mt = 0; mt < 2; ++mt)
#pragma unroll
    for (int nt = 0; nt < 2; ++nt){
        Bacc[mt][nt] = MFMA16(kB[mt][ks], kF[nt][ks], Bacc[mt][nt]);
        Aacc[mt][nt] = MFMA16(qF[mt][ks], kF[nt][ks], Aacc[mt][nt]);
    }
    f32x4 Rc[2][2];
#pragma unroll
    for (int mt = 0; mt < 2; ++mt)
#pragma unroll
    for (int nt = 0; nt < 2; ++nt)
#pragma unroll
    for (int rg = 0; rg < 4; ++rg){
        int row = 16*mt + 4*quad + rg, col = 16*nt + ln15;
        float av = (col <= row) ? Aacc[mt][nt][rg] : 0.f;
        Aw[((size_t)bc << 10) + row*32 + col] = f2bf(av);
        float bm = (col < row) ? -Bacc[mt][nt][rg] : 0.f;
        Ms[row][col] = bm;
        Rc[mt][nt][rg] = bm + ((col == row) ? 1.f : 0.f);
    }
    {
        unsigned short* kT = kwT + ((size_t)bc << 12);
#pragma unroll
        for (int t = 0; t < 8; ++t){
            unsigned short rj[8];
#pragma unroll
            for (int j = 0; j < 8; ++j)
                rj[j] = knS[(q8 + j) * 136 + ((q8 + j) >> 3) * 16 + 16*t + ln15];
            U8 kk;
            kk.u[0] = (unsigned)rj[0] | ((unsigned)rj[1] << 16);
            kk.u[1] = (unsigned)rj[2] | ((unsigned)rj[3] << 16);
            kk.u[2] = (unsigned)rj[4] | ((unsigned)rj[5] << 16);
            kk.u[3] = (unsigned)rj[6] | ((unsigned)rj[7] << 16);
            *(bf16x8*)(kT + (16*t + ln15) * 32 + q8) = kk.v;
        }
    }
#pragma unroll 1
    for (int rd = 0; rd < 4; ++rd){
        LGKM_WAIT();
        bf16x8 Am[2], Bm2[2];
#pragma unroll
        for (int mt = 0; mt < 2; ++mt) Am[mt] = afragF32(Ms, 16*mt + ln15, q8);
#pragma unroll
        for (int nt = 0; nt < 2; ++nt) Bm2[nt] = bfragF32(Ms, q8, 16*nt + ln15);
        f32x4 Mq[2][2];
#pragma unroll
        for (int mt = 0; mt < 2; ++mt)
#pragma unroll
        for (int nt = 0; nt < 2; ++nt)
            Mq[mt][nt] = MFMA16(Am[mt], Bm2[nt], Z);
#pragma unroll
        for (int mt = 0; mt < 2; ++mt)
#pragma unroll
        for (int nt = 0; nt < 2; ++nt)
#pragma unroll
        for (int rg = 0; rg < 4; ++rg){
            int row = 16*mt + 4*quad + rg, col = 16*nt + ln15;
            Rs[row][col] = Rc[mt][nt][rg];
            Ms[row][col] = Mq[mt][nt][rg];
        }
        LGKM_WAIT();
        bf16x8 Ar[2], Bq[2];
#pragma unroll
        for (int mt = 0; mt < 2; ++mt) Ar[mt] = afragF32(Rs, 16*mt + ln15, q8);
#pragma unroll
        for (int nt = 0; nt < 2; ++nt) Bq[nt] = bfragF32(Ms, q8, 16*nt + ln15);
#pragma unroll
        for (int mt = 0; mt < 2; ++mt)
#pragma unroll
        for (int nt = 0; nt < 2; ++nt)
            Rc[mt][nt] = MFMA16(Ar[mt], Bq[nt], Rc[mt][nt]);
    }
#pragma unroll
    for (int mt = 0; mt < 2; ++mt)
#pragma unroll
    for (int nt = 0; nt < 2; ++nt)
#pragma unroll
    for (int rg = 0; rg < 4; ++rg){
        int row = 16*mt + 4*quad + rg, col = 16*nt + ln15;
        Tw[((size_t)bc << 10) + row*32 + col] = f2bf(Rc[mt][nt][rg]);
    }
}

__global__ __launch_bounds__(64, 1)
void scan_fast(const float* __restrict__ v, const float* __restrict__ beta,
               const unsigned short* __restrict__ qw, const unsigned short* __restrict__ kw,
               const unsigned short* __restrict__ kwT,
               const unsigned short* __restrict__ Tw, const unsigned short* __restrict__ Aw,
               float* __restrict__ out)
{
    const int id = blockIdx.x;
    const int bh = id & 31, cb = id >> 5, c0 = cb * 16;
    const int l = threadIdx.x;
    const int quad = (l >> 4) & 3, ln15 = l & 15, q8 = quad * 8;
    const int hi = l >> 5;

    const f32x4 Z = {0.f, 0.f, 0.f, 0.f};
    f32x4 Sacc[8];
#pragma unroll
    for (int t = 0; t < 8; ++t) Sacc[t] = Z;

    const size_t bhL = (size_t)bh * L_SEQ;
    const int a0 = (((l & 16) << 1) | ln15) << 2;
    const int a1 = a0 + 64;

    bf16x8 cur[2][4], qA[2][4], knA[8], tA[2], aA[2], uB;
    float vr[8], br[8];

    auto quadswap = [&](int p0, int p1, int p2, int p3) -> bf16x8 {
        U8 r; int e, f;
        e = __builtin_amdgcn_ds_bpermute(a0, p0); f = __builtin_amdgcn_ds_bpermute(a0, p2);
        r.u[0] = (unsigned)(hi ? f : e);
        e = __builtin_amdgcn_ds_bpermute(a0, p1); f = __builtin_amdgcn_ds_bpermute(a0, p3);
        r.u[1] = (unsigned)(hi ? f : e);
        e = __builtin_amdgcn_ds_bpermute(a1, p0); f = __builtin_amdgcn_ds_bpermute(a1, p2);
        r.u[2] = (unsigned)(hi ? f : e);
        e = __builtin_amdgcn_ds_bpermute(a1, p1); f = __builtin_amdgcn_ds_bpermute(a1, p3);
        r.u[3] = (unsigned)(hi ? f : e);
        return r.v;
    };

    auto loadK = [&](int ch){
        const unsigned short* kp = kw + (bhL + (size_t)ch * CHUNK) * DK;
#pragma unroll
        for (int mt = 0; mt < 2; ++mt)
#pragma unroll
        for (int ks = 0; ks < 4; ++ks)
            cur[mt][ks] = *(const bf16x8*)(kp + (16*mt + ln15) * DK + 32*ks + q8);
    };
    auto loadQ = [&](int ch){
        const unsigned short* qp = qw + (bhL + (size_t)ch * CHUNK) * DK;
#pragma unroll
        for (int mt = 0; mt < 2; ++mt)
#pragma unroll
        for (int ks = 0; ks < 4; ++ks)
            qA[mt][ks] = *(const bf16x8*)(qp + (16*mt + ln15) * DK + 32*ks + q8);
    };
    auto loadT = [&](int ch){
        const unsigned short* Tp = Tw + ((size_t)(bh * NCH + ch) << 10);
#pragma unroll
        for (int mt = 0; mt < 2; ++mt)
            tA[mt] = *(const bf16x8*)(Tp + (16*mt + ln15) * 32 + q8);
    };
    auto loadA = [&](int ch){
        const unsigned short* Ap = Aw + ((size_t)(bh * NCH + ch) << 10);
#pragma unroll
        for (int mt = 0; mt < 2; ++mt)
            aA[mt] = *(const bf16x8*)(Ap + (16*mt + ln15) * 32 + q8);
    };
    auto loadVB = [&](int ch){
        const size_t row0 = bhL + (size_t)ch * CHUNK;
#pragma unroll
        for (int g = 0; g < 8; ++g){
            int i = 16*(g >> 2) + 4*quad + (g & 3);
            vr[g] = v[(row0 + i) * DV + c0 + ln15];
            br[g] = beta[row0 + i];
        }
    };
    auto loadKT = [&](int ch){
        const unsigned short* p = kwT + ((size_t)(bh * NCH + ch) << 12);
#pragma unroll
        for (int t = 0; t < 8; ++t)
            knA[t] = *(const bf16x8*)(p + (16*t + ln15) * 32 + q8);
    };

    loadK(0); loadQ(0); loadT(0); loadA(0); loadVB(0);
    {
        U8 z; z.u[0] = 0u; z.u[1] = 0u; z.u[2] = 0u; z.u[3] = 0u;
        uB = z.v;
#pragma unroll
        for (int t = 0; t < 8; ++t) knA[t] = z.v;
    }

    for (int ch = 0; ch < NCH; ++ch){
        const size_t row0 = bhL + (size_t)ch * CHUNK;
        const int chn = (ch + 1 < NCH) ? ch + 1 : NCH - 1;

#pragma unroll
        for (int t = 0; t < 8; ++t)
            Sacc[t] = MFMA16(knA[t], uB, Sacc[t]);
        loadKT(ch);

        int P[8][2];
#pragma unroll
        for (int t = 0; t < 8; ++t){
            P[t][0] = (int)pk2(Sacc[t][0], Sacc[t][1]);
            P[t][1] = (int)pk2(Sacc[t][2], Sacc[t][3]);
        }
        bf16x8 SB[4];
#pragma unroll
        for (int ks = 0; ks < 4; ++ks)
            SB[ks] = quadswap(P[2*ks][0], P[2*ks][1], P[2*ks+1][0], P[2*ks+1][1]);

        f32x4 Y[2] = {Z, Z}, Op[2] = {Z, Z};
#pragma unroll
        for (int ks = 0; ks < 4; ++ks)
#pragma unroll
        for (int mt = 0; mt < 2; ++mt){
            Y[mt]  = MFMA16(cur[mt][ks], SB[ks], Y[mt]);
            Op[mt] = MFMA16(qA[mt][ks],  SB[ks], Op[mt]);
        }
        loadK(chn); loadQ(chn);

        int PX0, PX1, PX2, PX3;
        {
            float x00 = br[0]*(vr[0]-Y[0][0]), x01 = br[1]*(vr[1]-Y[0][1]);
            float x02 = br[2]*(vr[2]-Y[0][2]), x03 = br[3]*(vr[3]-Y[0][3]);
            float x10 = br[4]*(vr[4]-Y[1][0]), x11 = br[5]*(vr[5]-Y[1][1]);
            float x12 = br[6]*(vr[6]-Y[1][2]), x13 = br[7]*(vr[7]-Y[1][3]);
            PX0 = (int)pk2(x00, x01); PX1 = (int)pk2(x02, x03);
            PX2 = (int)pk2(x10, x11); PX3 = (int)pk2(x12, x13);
        }
        bf16x8 Xb = quadswap(PX0, PX1, PX2, PX3);

        f32x4 U[2];
#pragma unroll
        for (int mt = 0; mt < 2; ++mt) U[mt] = MFMA16(tA[mt], Xb, Z);
        loadT(chn);

        {
            int PU0 = (int)pk2(U[0][0], U[0][1]), PU1 = (int)pk2(U[0][2], U[0][3]);
            int PU2 = (int)pk2(U[1][0], U[1][1]), PU3 = (int)pk2(U[1][2], U[1][3]);
            uB = quadswap(PU0, PU1, PU2, PU3);
        }

        f32x4 O[2];
#pragma unroll
        for (int mt = 0; mt < 2; ++mt) O[mt] = MFMA16(aA[mt], uB, Op[mt]);
#pragma unroll
        for (int mt = 0; mt < 2; ++mt)
#pragma unroll
        for (int rg = 0; rg < 4; ++rg)
            out[(row0 + 16*mt + 4*quad + rg) * DV + c0 + ln15] = O[mt][rg];

        loadA(chn);
        loadVB(chn);
    }
}

// ============== Fallback tier 2: fully fused single kernel =================

__global__ __launch_bounds__(512, 1)
void deltanet_fused(const float* __restrict__ q, const float* __restrict__ k,
                    const float* __restrict__ v, const float* __restrict__ beta,
                    float* __restrict__ out)
{
    const int bh = blockIdx.x;
    const int tid = threadIdx.x;
    const int n = L_SEQ / CHUNK;

    __shared__ float S[DK][DV + 1];
    __shared__ float qs[CHUNK][DK + 1];
    __shared__ float ks[CHUNK][DK + 1];
    __shared__ float vs[CHUNK][DV + 1];
    __shared__ float kbs[CHUNK][DK + 1];
    __shared__ float T[CHUNK][CHUNK + 1];
    __shared__ float at[CHUNK][CHUNK + 1];
    __shared__ float bet[CHUNK];

    for (int idx = tid; idx < DK * DV; idx += 512)
        S[idx / DV][idx % DV] = 0.f;
    __syncthreads();

    const size_t base_bh = (size_t)bh * L_SEQ;

    for (int ch = 0; ch < n; ++ch){
        const size_t row0 = base_bh + (size_t)ch * CHUNK;
        for (int idx = tid; idx < CHUNK * DK; idx += 512){
            int r = idx >> 7, c = idx & 127;
            size_t g = (row0 + (size_t)r) * DK + c;
            qs[r][c] = q[g]; ks[r][c] = k[g]; vs[r][c] = v[g];
        }
        if (tid < CHUNK) bet[tid] = beta[row0 + tid];
        __syncthreads();
        if (tid < 64){
            int r = tid & 31;
            const float* src = (tid < 32) ? &qs[r][0] : &ks[r][0];
            float s = 0.f;
            for (int d = 0; d < DK; ++d){ float x = src[d]; s += x * x; }
            at[(tid < 32) ? 0 : 1][r] = 1.0f / sqrtf(s + 1e-6f);
        }
        __syncthreads();
        for (int idx = tid; idx < CHUNK * DK; idx += 512){
            int r = idx >> 7, c = idx & 127;
            float qq = qs[r][c] * at[0][r];
            float kk = ks[r][c] * at[1][r];
            float b = bet[r];
            qs[r][c] = qq; ks[r][c] = kk; kbs[r][c] = kk * b; vs[r][c] *= b;
        }
        __syncthreads();
        for (int idx = tid; idx < CHUNK * CHUNK; idx += 512){
            int i = idx >> 5, j = idx & 31;
            float s = 0.f;
            if (j < i){
                for (int d = 0; d < DK; ++d) s += kbs[i][d] * ks[j][d];
                s = -s;
            }
            T[i][j] = s;
        }
        __syncthreads();
        for (int i = 1; i < CHUNK; ++i){
            float upd = 0.f;
            if (tid < i){
                int j = tid;
                for (int kk = j + 1; kk < i; ++kk) upd += T[i][kk] * T[kk][j];
            }
            __syncthreads();
            if (tid < i) T[i][tid] += upd;
            __syncthreads();
        }
        if (tid < CHUNK) T[tid][tid] = 1.0f;
        __syncthreads();
        {
            int c = tid & 127;
            int i0 = (tid >> 7) * 8;
            float uacc[8], wacc[8];
#pragma unroll
            for (int r = 0; r < 8; ++r){ uacc[r] = 0.f; wacc[r] = 0.f; }
            for (int j = 0; j < CHUNK; ++j){
                float vvv = vs[j][c], kb = kbs[j][c];
#pragma unroll
                for (int r = 0; r < 8; ++r){
                    float tt = T[i0 + r][j];
                    uacc[r] += tt * vvv; wacc[r] += tt * kb;
                }
            }
            __syncthreads();
#pragma unroll
            for (int r = 0; r < 8; ++r){ vs[i0 + r][c] = uacc[r]; kbs[i0 + r][c] = wacc[r]; }
        }
        __syncthreads();
        for (int idx = tid; idx < CHUNK * CHUNK; idx += 512){
            int i = idx >> 5, j = idx & 31;
            float s = 0.f;
            if (j <= i) for (int d = 0; d < DK; ++d) s += qs[i][d] * ks[j][d];
            at[i][j] = s;
        }
        __syncthreads();
        {
            int c = tid & 127;
            int i0 = (tid >> 7) * 8;
            float acc[8];
#pragma unroll
            for (int r = 0; r < 8; ++r) acc[r] = 0.f;
            for (int d = 0; d < DK; ++d){
                float sv = S[d][c];
#pragma unroll
                for (int r = 0; r < 8; ++r) acc[r] += kbs[i0 + r][d] * sv;
            }
#pragma unroll
            for (int r = 0; r < 8; ++r) vs[i0 + r][c] -= acc[r];
        }
        __syncthreads();
        {
            int c = tid & 127;
            int i0 = (tid >> 7) * 8;
            float acc[8];
#pragma unroll
            for (int r = 0; r < 8; ++r) acc[r] = 0.f;
            for (int d = 0; d < DK; ++d){
                float sv = S[d][c];
#pragma unroll
                for (int r = 0; r < 8; ++r) acc[r] += qs[i0 + r][d] * sv;
            }
            for (int j = 0; j < CHUNK; ++j){
                float uv = vs[j][c];
#pragma unroll
                for (int r = 0; r < 8; ++r) acc[r] += at[i0 + r][j] * uv;
            }
#pragma unroll
            for (int r = 0; r < 8; ++r)
                out[(row0 + (size_t)(i0 + r)) * DV + c] = acc[r];
        }
        __syncthreads();
        {
            int c = tid & 127;
            int d0 = (tid >> 7) * 32;
            float acc[32];
#pragma unroll
            for (int r = 0; r < 32; ++r) acc[r] = 0.f;
            for (int i = 0; i < CHUNK; ++i){
                float uv = vs[i][c];
#pragma unroll
                for (int r = 0; r < 32; ++r) acc[r] += ks[i][d0 + r] * uv;
            }
#pragma unroll
            for (int r = 0; r < 32; ++r) S[d0 + r][c] += acc[r];
        }
        __syncthreads();
    }
}

extern "C" void kernel_launch(void* const* d_in, const int* in_sizes, int n_in,
                              void* d_out, int out_size, void* d_ws, size_t ws_size,
                              hipStream_t stream) {
    const float* q = (const float*)d_in[0];
    const float* k = (const float*)d_in[1];
    const float* v = (const float*)d_in[2];
    const float* beta = (const float*)d_in[3];
    float* out = (float*)d_out;

    const size_t QK = (size_t)BH * L_SEQ * DK;        // 16,777,216 shorts
    const size_t TA = (size_t)BH * NCH * 1024;        //  4,194,304 shorts
    const size_t TB = (size_t)BH * NSC * 1024;        //  2,097,152 shorts
    const size_t need64 = (3*QK + 2*TA + 2*TB) * sizeof(unsigned short); // ~125.8 MB
    const size_t need32 = (3*QK + 2*TA) * sizeof(unsigned short);        // ~117.4 MB

    if (ws_size >= need64){
        unsigned short* qwp = (unsigned short*)d_ws;
        unsigned short* kwp = qwp + QK;
        unsigned short* Twp = kwp + QK;
        unsigned short* Awp = Twp + TA;
        unsigned short* kTp = Awp + TA;
        unsigned short* Gwp = kTp + QK;
        unsigned short* Fwp = Gwp + TB;
        prep64_kernel<<<BH * NSC, 64, 0, stream>>>(q, k, beta, qwp, kwp, Twp, Awp, kTp, Gwp, Fwp);
        scan64<<<BH * 8, 64, 0, stream>>>(v, beta, qwp, kwp, kTp, Twp, Awp, Gwp, Fwp, out);
    } else if (ws_size >= need32){
        unsigned short* qwp = (unsigned short*)d_ws;
        unsigned short* kwp = qwp + QK;
        unsigned short* Twp = kwp + QK;
        unsigned short* Awp = Twp + TA;
        unsigned short* kTp = Awp + TA;
        prep_kernel<<<BH * NCH, 64, 0, stream>>>(q, k, beta, qwp, kwp, Twp, Awp, kTp);
        scan_fast<<<BH * 8, 64, 0, stream>>>(v, beta, qwp, kwp, kTp, Twp, Awp, out);
    } else {
        deltanet_fused<<<BH, 512, 0, stream>>>(q, k, v, beta, out);
    }
}